// Round 3
// baseline (5170.366 us; speedup 1.0000x reference)
//
#include <hip/hip_runtime.h>
#include <hip/hip_fp16.h>

#define NN 50000
#define NP 400000
#define NEDGE 800000
#define IND 256
#define HD 128
#define NC 10
#define TBP 10

typedef _Float16 f16;
typedef _Float16 f16x8 __attribute__((ext_vector_type(8)));
typedef unsigned short u16x8 __attribute__((ext_vector_type(8)));
typedef float f32x4 __attribute__((ext_vector_type(4)));

// ---- workspace offsets (bytes, all 16B-aligned) ----
static constexpr size_t OFF_R      = 0;          // 128 f32: R[100], [100]=alpha
static constexpr size_t OFF_H      = 512;        // h fp16 [NN][128]
static constexpr size_t OFF_LOGPHI = 12800512;   // [NN][10] f32
static constexpr size_t OFF_DEG    = 14800512;   // [NN] f32
static constexpr size_t OFF_LOGDEG = 15000512;   // [NN] f32
static constexpr size_t OFF_RSQ    = 15200512;   // [NN] f32
static constexpr size_t OFF_WPAIR  = 15400512;   // [NP] f32
static constexpr size_t OFF_EN     = 17000512;   // [NP] f32
static constexpr size_t OFF_M      = 18600512;   // SoA [10][NEDGE] f32
static constexpr size_t OFF_LOGF   = 50600512;   // SoA [10][NEDGE] f32
static constexpr size_t OFF_SUMIN  = 82600512;   // [NN][10] f32
static constexpr size_t OFF_W1T    = 84600512;   // W1 transposed fp16 [64][256]

// ---------------- setup: R matrix, alpha, W1 transpose ----------------
__global__ __launch_bounds__(256) void k_setup(const float* __restrict__ Rraw,
    const float* __restrict__ rsl, const float* __restrict__ ml,
    const float* __restrict__ mw1, float* __restrict__ Rbuf, f16* __restrict__ w1t) {
  int tid = threadIdx.x;
  if (tid < 100) {
    int c = tid / 10, d = tid % 10;
    float scale = log1pf(expf(rsl[0])) + 1e-6f;
    Rbuf[tid] = scale * tanhf(0.5f * (Rraw[c * 10 + d] + Rraw[d * 10 + c]));
  } else if (tid == 100) {
    Rbuf[100] = 1.5f * (1.f / (1.f + expf(-ml[0])));  // ALPHA_MAX*sigmoid*ALPHA_SCALE
  }
  for (int idx = tid; idx < 64 * 256; idx += 256) {
    int j = idx >> 8, k = idx & 255;
    w1t[idx] = (f16)mw1[k * 64 + j];
  }
}

// ---------------- degree / node post ----------------
__global__ __launch_bounds__(256) void k_deg(const int* __restrict__ ei, float* __restrict__ deg) {
  int e = blockIdx.x * 256 + threadIdx.x;
  if (e < NEDGE) atomicAdd(&deg[ei[e]], 1.f);
}

__global__ __launch_bounds__(256) void k_nodepost(const float* __restrict__ deg,
    float* __restrict__ logdeg, float* __restrict__ rsq) {
  int i = blockIdx.x * 256 + threadIdx.x;
  if (i >= NN) return;
  float d = deg[i];
  logdeg[i] = __logf(d + 1.f);
  rsq[i] = rsqrtf(fmaxf(d, 1.f));
}

// ---------------- encoder: h = relu(x @ W1 + b1), store fp16 ----------------
__global__ __launch_bounds__(256) void k_encoder(const float* __restrict__ x,
    const float* __restrict__ w1, const float* __restrict__ b1, f16* __restrict__ h) {
  __shared__ float xs[16 * IND];
  const int tid = threadIdx.x;
  const int nb = blockIdx.x * 16;
  {
    const float4* src = (const float4*)(x + (size_t)nb * IND);
    float4* dst4 = (float4*)xs;
#pragma unroll
    for (int i = 0; i < 4; i++) dst4[tid + 256 * i] = src[tid + 256 * i];
  }
  __syncthreads();
  const int j = tid & (HD - 1);
  const int g = tid >> 7;
  float acc[8] = {0, 0, 0, 0, 0, 0, 0, 0};
  const float4* xs4 = (const float4*)xs;
  for (int k0 = 0; k0 < IND; k0 += 4) {
    float wa = w1[(k0 + 0) * HD + j];
    float wb = w1[(k0 + 1) * HD + j];
    float wc = w1[(k0 + 2) * HD + j];
    float wd = w1[(k0 + 3) * HD + j];
#pragma unroll
    for (int n = 0; n < 8; n++) {
      float4 xv = xs4[(g * 8 + n) * (IND / 4) + (k0 >> 2)];
      acc[n] += xv.x * wa + xv.y * wb + xv.z * wc + xv.w * wd;
    }
  }
  float bj = b1[j];
#pragma unroll
  for (int n = 0; n < 8; n++) {
    float v = fmaxf(acc[n] + bj, 0.f);
    h[(size_t)(nb + g * 8 + n) * HD + j] = (f16)v;
  }
}

// ---------------- logits + log_softmax(logits/1.5) ----------------
__global__ __launch_bounds__(256) void k_logits(const f16* __restrict__ h,
    const float* __restrict__ w2, const float* __restrict__ b2, float* __restrict__ logphi) {
  __shared__ float hs[16 * HD];
  __shared__ float lg[16 * NC];
  const int tid = threadIdx.x;
  const int nb = blockIdx.x * 16;
  for (int i = tid; i < 16 * HD / 8; i += 256) {
    f16x8 v = *(const f16x8*)(h + (size_t)nb * HD + i * 8);
#pragma unroll
    for (int u = 0; u < 8; u++) hs[i * 8 + u] = (float)v[u];
  }
  __syncthreads();
  if (tid < 160) {
    int n = tid / 10, c = tid % 10;
    float a = b2[c];
    for (int k = 0; k < HD; k++) a += hs[n * HD + k] * w2[k * NC + c];
    lg[n * NC + c] = a * (1.f / 1.5f);
  }
  __syncthreads();
  if (tid < 16) {
    float mx = -1e30f;
#pragma unroll
    for (int c = 0; c < NC; c++) mx = fmaxf(mx, lg[tid * NC + c]);
    float s = 0.f;
#pragma unroll
    for (int c = 0; c < NC; c++) s += __expf(lg[tid * NC + c] - mx);
    float lse = __logf(s) + mx;
#pragma unroll
    for (int c = 0; c < NC; c++)
      logphi[(size_t)(nb + tid) * NC + c] = lg[tid * NC + c] - lse;
  }
}

// ---------------- edge MLP (per undirected pair), MFMA f16 ----------------
__global__ __launch_bounds__(256) void k_edge_mlp(const f16* __restrict__ h,
    const int* __restrict__ ei, const float* __restrict__ logdeg, const float* __restrict__ rsq,
    const f16* __restrict__ w1t, const float* __restrict__ mw1, const float* __restrict__ mb1,
    const float* __restrict__ mw2, const float* __restrict__ mb2,
    float* __restrict__ w_pair, float* __restrict__ en_pair) {
  __shared__ f16 At[4][16 * 264];        // per-wave A tile [16 rows][256 k], stride 264
  __shared__ float hidl[4][16 * 64];     // per-wave hidden tile
  __shared__ float sfeat[4][2][16];      // struct features per row
  const int tid = threadIdx.x;
  const int wid = tid >> 6;
  const int lane = tid & 63;
  const int l15 = lane & 15;
  const int lhi = lane >> 4;

  // persistent B fragments: W1t[j][k], j = l15+16t, k = ks*32 + lhi*8 (+0..7)
  f16x8 bfr[8][4];
#pragma unroll
  for (int ks = 0; ks < 8; ks++)
#pragma unroll
    for (int t = 0; t < 4; t++)
      bfr[ks][t] = *(const f16x8*)(w1t + (size_t)(l15 + 16 * t) * 256 + ks * 32 + lhi * 8);

  float b1v[4], w256v[4], w257v[4];
#pragma unroll
  for (int t = 0; t < 4; t++) {
    b1v[t] = mb1[l15 + 16 * t];
    w256v[t] = mw1[256 * 64 + l15 + 16 * t];
    w257v[t] = mw1[257 * 64 + l15 + 16 * t];
  }
  float w2r[16];
#pragma unroll
  for (int jj = 0; jj < 16; jj++) w2r[jj] = mw2[lhi * 16 + jj];
  const float b2s = mb2[0];

  const int ntiles = NP / 64;  // 6250
  for (int tile = blockIdx.x; tile < ntiles; tile += gridDim.x) {
    const int pbase = tile * 64 + wid * 16;
    // stage A tile: rows = pairs, k<128: hs*hd, 128..255: |hs-hd|
#pragma unroll
    for (int rr = 0; rr < 4; rr++) {
      int r = rr * 4 + lhi;
      int p = pbase + r;
      int s = ei[p], d = ei[NEDGE + p];
      f16x8 hv = *(const f16x8*)(h + (size_t)s * HD + l15 * 8);
      f16x8 gv = *(const f16x8*)(h + (size_t)d * HD + l15 * 8);
      f16x8 pv = hv * gv;
      f16x8 qv = hv - gv;
      u16x8 qb = *(u16x8*)&qv;
#pragma unroll
      for (int u = 0; u < 8; u++) qb[u] &= 0x7FFF;
      qv = *(f16x8*)&qb;
      *(f16x8*)(&At[wid][r * 264 + l15 * 8]) = pv;
      *(f16x8*)(&At[wid][r * 264 + 128 + l15 * 8]) = qv;
    }
    if (lane < 16) {
      int p = pbase + lane;
      int s = ei[p], d = ei[NEDGE + p];
      float a = logdeg[s], b = logdeg[d];
      sfeat[wid][0][lane] = a + b;
      sfeat[wid][1][lane] = fabsf(a - b);
      en_pair[p] = rsq[s] * rsq[d];
    }
    __syncthreads();
    f32x4 acc[4] = {{0.f, 0.f, 0.f, 0.f}, {0.f, 0.f, 0.f, 0.f},
                    {0.f, 0.f, 0.f, 0.f}, {0.f, 0.f, 0.f, 0.f}};
#pragma unroll
    for (int ks = 0; ks < 8; ks++) {
      f16x8 af = *(const f16x8*)(&At[wid][l15 * 264 + ks * 32 + lhi * 8]);
#pragma unroll
      for (int t = 0; t < 4; t++)
        acc[t] = __builtin_amdgcn_mfma_f32_16x16x32_f16(af, bfr[ks][t], acc[t], 0, 0, 0);
    }
    // epilogue: struct rank-2 correction + bias + relu -> hid LDS
#pragma unroll
    for (int t = 0; t < 4; t++) {
#pragma unroll
      for (int i = 0; i < 4; i++) {
        int r = lhi * 4 + i;  // C/D layout: row=(lane>>4)*4+reg, col=lane&15 (+16t)
        float v = acc[t][i] + sfeat[wid][0][r] * w256v[t] + sfeat[wid][1][r] * w257v[t] + b1v[t];
        hidl[wid][r * 64 + l15 + 16 * t] = fmaxf(v, 0.f);
      }
    }
    __syncthreads();
    {
      // layer 2: w_raw[r] = sum_j hid[r][j]*W2[j] + b2 ; 4-way partial + shfl reduce
      float sacc = 0.f;
#pragma unroll
      for (int jj = 0; jj < 16; jj++) sacc += hidl[wid][l15 * 64 + lhi * 16 + jj] * w2r[jj];
      sacc += __shfl_xor(sacc, 16);
      sacc += __shfl_xor(sacc, 32);
      if (lane < 16) {
        float wr = sacc + b2s;
        w_pair[pbase + lane] = 0.8f / (1.f + __expf(-wr));  // W_MAX*sigmoid
      }
    }
    __syncthreads();
  }
}

// ---------------- m0 = exp(log_phi[src]) ----------------
__global__ __launch_bounds__(256) void k_m0(const int* __restrict__ ei,
    const float* __restrict__ logphi, float* __restrict__ m) {
  int e = blockIdx.x * 256 + threadIdx.x;
  if (e >= NEDGE) return;
  int s = ei[e];
#pragma unroll
  for (int c = 0; c < NC; c++) m[(size_t)c * NEDGE + e] = __expf(logphi[s * NC + c]);
}

// ---------------- BP message: f, log_f, scatter sum_in ----------------
__global__ __launch_bounds__(256) void k_bp_f(const float* __restrict__ m,
    const float* __restrict__ wp, const float* __restrict__ enp, const int* __restrict__ ei,
    const float* __restrict__ Rbuf, float* __restrict__ log_f, float* __restrict__ sum_in) {
  __shared__ float Rs[100];
  if (threadIdx.x < 100) Rs[threadIdx.x] = Rbuf[threadIdx.x];
  __syncthreads();
  int e = blockIdx.x * 256 + threadIdx.x;
  if (e >= NEDGE) return;
  int p = (e < NP) ? e : e - NP;
  float w = wp[p], en = enp[p];
  float f[NC] = {0, 0, 0, 0, 0, 0, 0, 0, 0, 0};
#pragma unroll
  for (int c = 0; c < NC; c++) {
    float mc = m[(size_t)c * NEDGE + e];
#pragma unroll
    for (int d = 0; d < NC; d++) {
      float xv = w * Rs[c * NC + d];
      xv = fminf(fmaxf(xv, -20.f), 20.f);
      f[d] += mc * __expf(xv);
    }
  }
  int dn = ei[NEDGE + e];
#pragma unroll
  for (int d = 0; d < NC; d++) {
    float lf = __logf(fmaxf(f[d], 1e-12f)) * en;
    log_f[(size_t)d * NEDGE + e] = lf;
    atomicAdd(&sum_in[dn * NC + d], lf);
  }
}

// ---------------- BP update: m mix + renorm ----------------
__global__ __launch_bounds__(256) void k_bp_upd(float* __restrict__ m,
    const float* __restrict__ log_f, const float* __restrict__ sum_in,
    const float* __restrict__ logphi, const int* __restrict__ ei,
    const float* __restrict__ Rbuf) {
  int e = blockIdx.x * 256 + threadIdx.x;
  if (e >= NEDGE) return;
  int s = ei[e];
  int re = (e < NP) ? e + NP : e - NP;  // rev[e] by construction
  float alpha = Rbuf[100];
  float t[NC];
  float mx = -1e30f;
#pragma unroll
  for (int c = 0; c < NC; c++) {
    float excl = sum_in[s * NC + c] - log_f[(size_t)c * NEDGE + re];
    float v = logphi[s * NC + c] + alpha * excl;
    t[c] = v;
    mx = fmaxf(mx, v);
  }
  float ssum = 0.f;
#pragma unroll
  for (int c = 0; c < NC; c++) { float ev = __expf(t[c] - mx); t[c] = ev; ssum += ev; }
  float inv = 1.f / ssum;
  float nsum = 0.f;
#pragma unroll
  for (int c = 0; c < NC; c++) {
    float mm = 0.8f * m[(size_t)c * NEDGE + e] + 0.2f * (t[c] * inv);
    mm = fmaxf(mm, 1e-12f);
    t[c] = mm;
    nsum += mm;
  }
  float inv2 = 1.f / nsum;
#pragma unroll
  for (int c = 0; c < NC; c++) m[(size_t)c * NEDGE + e] = t[c] * inv2;
}

// ---------------- final beliefs ----------------
__global__ __launch_bounds__(256) void k_beliefs(const float* __restrict__ logphi,
    const float* __restrict__ sum_in, const float* __restrict__ Rbuf, float* __restrict__ out) {
  int n = blockIdx.x * 256 + threadIdx.x;
  if (n >= NN) return;
  float alpha = Rbuf[100];
  float t[NC];
  float mx = -1e30f;
#pragma unroll
  for (int c = 0; c < NC; c++) {
    float v = logphi[n * NC + c] + alpha * sum_in[n * NC + c];
    t[c] = v;
    mx = fmaxf(mx, v);
  }
  float ssum = 0.f;
#pragma unroll
  for (int c = 0; c < NC; c++) { float ev = __expf(t[c] - mx); t[c] = ev; ssum += ev; }
  float inv = 1.f / ssum;
#pragma unroll
  for (int c = 0; c < NC; c++) out[(size_t)n * NC + c] = t[c] * inv;
}

extern "C" void kernel_launch(void* const* d_in, const int* in_sizes, int n_in,
                              void* d_out, int out_size, void* d_ws, size_t ws_size,
                              hipStream_t stream) {
  const float* x    = (const float*)d_in[0];
  const int*   ei   = (const int*)d_in[1];
  const float* ew1  = (const float*)d_in[3];
  const float* eb1  = (const float*)d_in[4];
  const float* ew2  = (const float*)d_in[5];
  const float* eb2  = (const float*)d_in[6];
  const float* mw1  = (const float*)d_in[7];
  const float* mb1  = (const float*)d_in[8];
  const float* mw2  = (const float*)d_in[9];
  const float* mb2  = (const float*)d_in[10];
  const float* Rraw = (const float*)d_in[11];
  const float* rsl  = (const float*)d_in[12];
  const float* ml   = (const float*)d_in[13];
  float* out = (float*)d_out;

  char* ws = (char*)d_ws;
  float* Rbuf   = (float*)(ws + OFF_R);
  f16*   h      = (f16*)(ws + OFF_H);
  float* logphi = (float*)(ws + OFF_LOGPHI);
  float* deg    = (float*)(ws + OFF_DEG);
  float* logdeg = (float*)(ws + OFF_LOGDEG);
  float* rsq    = (float*)(ws + OFF_RSQ);
  float* wpair  = (float*)(ws + OFF_WPAIR);
  float* enp    = (float*)(ws + OFF_EN);
  float* m      = (float*)(ws + OFF_M);
  float* logf_  = (float*)(ws + OFF_LOGF);
  float* sumin  = (float*)(ws + OFF_SUMIN);
  f16*   w1t    = (f16*)(ws + OFF_W1T);

  k_setup<<<1, 256, 0, stream>>>(Rraw, rsl, ml, mw1, Rbuf, w1t);
  hipMemsetAsync(deg, 0, NN * sizeof(float), stream);
  k_deg<<<NEDGE / 256, 256, 0, stream>>>(ei, deg);
  k_nodepost<<<(NN + 255) / 256, 256, 0, stream>>>(deg, logdeg, rsq);
  k_encoder<<<NN / 16, 256, 0, stream>>>(x, ew1, eb1, h);
  k_logits<<<NN / 16, 256, 0, stream>>>(h, ew2, eb2, logphi);
  k_edge_mlp<<<512, 256, 0, stream>>>(h, ei, logdeg, rsq, w1t, mw1, mb1, mw2, mb2, wpair, enp);
  k_m0<<<NEDGE / 256, 256, 0, stream>>>(ei, logphi, m);

  for (int it = 0; it < TBP; it++) {
    hipMemsetAsync(sumin, 0, NN * NC * sizeof(float), stream);
    k_bp_f<<<NEDGE / 256, 256, 0, stream>>>(m, wpair, enp, ei, Rbuf, logf_, sumin);
    k_bp_upd<<<NEDGE / 256, 256, 0, stream>>>(m, logf_, sumin, logphi, ei, Rbuf);
  }
  hipMemsetAsync(sumin, 0, NN * NC * sizeof(float), stream);
  k_bp_f<<<NEDGE / 256, 256, 0, stream>>>(m, wpair, enp, ei, Rbuf, logf_, sumin);
  k_beliefs<<<(NN + 255) / 256, 256, 0, stream>>>(logphi, sumin, Rbuf, out);
}

// Round 4
// 1356.852 us; speedup vs baseline: 3.8106x; 3.8106x over previous
//
#include <hip/hip_runtime.h>
#include <hip/hip_fp16.h>

#define NN 50000
#define NP 400000
#define NEDGE 800000
#define IND 256
#define HD 128
#define NC 10
#define TBP 10

typedef _Float16 f16;
typedef _Float16 f16x8 __attribute__((ext_vector_type(8)));
typedef unsigned short u16x8 __attribute__((ext_vector_type(8)));
typedef float f32x4 __attribute__((ext_vector_type(4)));

// ---- workspace offsets (bytes) ----
static constexpr size_t OFF_R      = 0;          // 128 f32: R[100], [100]=alpha
static constexpr size_t OFF_H      = 512;        // h fp16 [NN][128] (dead after edge_mlp)
static constexpr size_t OFF_OFFS   = 512;            // CSR off int[NN+1]   (aliases h)
static constexpr size_t OFF_CUR    = 512 + 200016;   // CSR cursor int[NN]  (aliases h)
static constexpr size_t OFF_CSR    = 512 + 400032;   // CSR edge ids int[NEDGE] (aliases h)
static constexpr size_t OFF_LOGPHI = 12800512;   // [NN][10] f32
static constexpr size_t OFF_DEG    = 14800512;   // [NN] f32
static constexpr size_t OFF_LOGDEG = 15000512;   // [NN] f32
static constexpr size_t OFF_RSQ    = 15200512;   // [NN] f32
static constexpr size_t OFF_WPAIR  = 15400512;   // [NP] f32
static constexpr size_t OFF_EN     = 17000512;   // [NP] f32
static constexpr size_t OFF_M      = 18600512;   // m edge-major [NEDGE][10] f32 (32MB)
static constexpr size_t OFF_L      = 50600512;   // log_f edge-major [NEDGE][10] f32 (32MB)
static constexpr size_t OFF_SUMIN  = 82600512;   // [NN][10] f32
static constexpr size_t OFF_W1T    = 84600512;   // W1 transposed fp16 [64][256]

// ---------------- setup: R matrix, alpha, W1 transpose ----------------
__global__ __launch_bounds__(256) void k_setup(const float* __restrict__ Rraw,
    const float* __restrict__ rsl, const float* __restrict__ ml,
    const float* __restrict__ mw1, float* __restrict__ Rbuf, f16* __restrict__ w1t) {
  int tid = threadIdx.x;
  if (tid < 100) {
    int c = tid / 10, d = tid % 10;
    float scale = log1pf(expf(rsl[0])) + 1e-6f;
    Rbuf[tid] = scale * tanhf(0.5f * (Rraw[c * 10 + d] + Rraw[d * 10 + c]));
  } else if (tid == 100) {
    Rbuf[100] = 1.5f * (1.f / (1.f + expf(-ml[0])));  // ALPHA_MAX*sigmoid*ALPHA_SCALE
  }
  for (int idx = tid; idx < 64 * 256; idx += 256) {
    int j = idx >> 8, k = idx & 255;
    w1t[idx] = (f16)mw1[k * 64 + j];
  }
}

// ---------------- degree / node post ----------------
__global__ __launch_bounds__(256) void k_deg(const int* __restrict__ ei, float* __restrict__ deg) {
  int e = blockIdx.x * 256 + threadIdx.x;
  if (e < NEDGE) atomicAdd(&deg[ei[e]], 1.f);
}

__global__ __launch_bounds__(256) void k_nodepost(const float* __restrict__ deg,
    float* __restrict__ logdeg, float* __restrict__ rsq) {
  int i = blockIdx.x * 256 + threadIdx.x;
  if (i >= NN) return;
  float d = deg[i];
  logdeg[i] = __logf(d + 1.f);
  rsq[i] = rsqrtf(fmaxf(d, 1.f));
}

// ---------------- CSR build: scan + fill ----------------
__global__ __launch_bounds__(1024) void k_scan(const float* __restrict__ deg,
    int* __restrict__ off, int* __restrict__ cursor) {
  __shared__ int sums[1024];
  const int t = threadIdx.x;
  const int base = t * 49;
  int mysum = 0;
#pragma unroll 1
  for (int i = 0; i < 49; i++) {
    int idx = base + i;
    if (idx < NN) mysum += (int)deg[idx];
  }
  sums[t] = mysum;
  __syncthreads();
  for (int d = 1; d < 1024; d <<= 1) {
    int v = (t >= d) ? sums[t - d] : 0;
    __syncthreads();
    sums[t] += v;
    __syncthreads();
  }
  int run = sums[t] - mysum;  // exclusive base for this chunk
#pragma unroll 1
  for (int i = 0; i < 49; i++) {
    int idx = base + i;
    if (idx < NN) {
      off[idx] = run;
      cursor[idx] = run;
      run += (int)deg[idx];
    }
  }
  if (t == 1023) off[NN] = sums[1023];
}

__global__ __launch_bounds__(256) void k_fill(const int* __restrict__ ei,
    int* __restrict__ cursor, int* __restrict__ csr) {
  int e = blockIdx.x * 256 + threadIdx.x;
  if (e >= NEDGE) return;
  int d = ei[NEDGE + e];
  int pos = atomicAdd(&cursor[d], 1);
  csr[pos] = e;
}

// ---------------- encoder: h = relu(x @ W1 + b1), store fp16 ----------------
__global__ __launch_bounds__(256) void k_encoder(const float* __restrict__ x,
    const float* __restrict__ w1, const float* __restrict__ b1, f16* __restrict__ h) {
  __shared__ float xs[16 * IND];
  const int tid = threadIdx.x;
  const int nb = blockIdx.x * 16;
  {
    const float4* src = (const float4*)(x + (size_t)nb * IND);
    float4* dst4 = (float4*)xs;
#pragma unroll
    for (int i = 0; i < 4; i++) dst4[tid + 256 * i] = src[tid + 256 * i];
  }
  __syncthreads();
  const int j = tid & (HD - 1);
  const int g = tid >> 7;
  float acc[8] = {0, 0, 0, 0, 0, 0, 0, 0};
  const float4* xs4 = (const float4*)xs;
  for (int k0 = 0; k0 < IND; k0 += 4) {
    float wa = w1[(k0 + 0) * HD + j];
    float wb = w1[(k0 + 1) * HD + j];
    float wc = w1[(k0 + 2) * HD + j];
    float wd = w1[(k0 + 3) * HD + j];
#pragma unroll
    for (int n = 0; n < 8; n++) {
      float4 xv = xs4[(g * 8 + n) * (IND / 4) + (k0 >> 2)];
      acc[n] += xv.x * wa + xv.y * wb + xv.z * wc + xv.w * wd;
    }
  }
  float bj = b1[j];
#pragma unroll
  for (int n = 0; n < 8; n++) {
    float v = fmaxf(acc[n] + bj, 0.f);
    h[(size_t)(nb + g * 8 + n) * HD + j] = (f16)v;
  }
}

// ---------------- logits + log_softmax(logits/1.5) ----------------
__global__ __launch_bounds__(256) void k_logits(const f16* __restrict__ h,
    const float* __restrict__ w2, const float* __restrict__ b2, float* __restrict__ logphi) {
  __shared__ float hs[16 * HD];
  __shared__ float lg[16 * NC];
  const int tid = threadIdx.x;
  const int nb = blockIdx.x * 16;
  for (int i = tid; i < 16 * HD / 8; i += 256) {
    f16x8 v = *(const f16x8*)(h + (size_t)nb * HD + i * 8);
#pragma unroll
    for (int u = 0; u < 8; u++) hs[i * 8 + u] = (float)v[u];
  }
  __syncthreads();
  if (tid < 160) {
    int n = tid / 10, c = tid % 10;
    float a = b2[c];
    for (int k = 0; k < HD; k++) a += hs[n * HD + k] * w2[k * NC + c];
    lg[n * NC + c] = a * (1.f / 1.5f);
  }
  __syncthreads();
  if (tid < 16) {
    float mx = -1e30f;
#pragma unroll
    for (int c = 0; c < NC; c++) mx = fmaxf(mx, lg[tid * NC + c]);
    float s = 0.f;
#pragma unroll
    for (int c = 0; c < NC; c++) s += __expf(lg[tid * NC + c] - mx);
    float lse = __logf(s) + mx;
#pragma unroll
    for (int c = 0; c < NC; c++)
      logphi[(size_t)(nb + tid) * NC + c] = lg[tid * NC + c] - lse;
  }
}

// ---------------- edge MLP (per undirected pair), MFMA f16 ----------------
__global__ __launch_bounds__(256) void k_edge_mlp(const f16* __restrict__ h,
    const int* __restrict__ ei, const float* __restrict__ logdeg, const float* __restrict__ rsq,
    const f16* __restrict__ w1t, const float* __restrict__ mw1, const float* __restrict__ mb1,
    const float* __restrict__ mw2, const float* __restrict__ mb2,
    float* __restrict__ w_pair, float* __restrict__ en_pair) {
  __shared__ f16 At[4][16 * 264];
  __shared__ float hidl[4][16 * 64];
  __shared__ float sfeat[4][2][16];
  const int tid = threadIdx.x;
  const int wid = tid >> 6;
  const int lane = tid & 63;
  const int l15 = lane & 15;
  const int lhi = lane >> 4;

  f16x8 bfr[8][4];
#pragma unroll
  for (int ks = 0; ks < 8; ks++)
#pragma unroll
    for (int t = 0; t < 4; t++)
      bfr[ks][t] = *(const f16x8*)(w1t + (size_t)(l15 + 16 * t) * 256 + ks * 32 + lhi * 8);

  float b1v[4], w256v[4], w257v[4];
#pragma unroll
  for (int t = 0; t < 4; t++) {
    b1v[t] = mb1[l15 + 16 * t];
    w256v[t] = mw1[256 * 64 + l15 + 16 * t];
    w257v[t] = mw1[257 * 64 + l15 + 16 * t];
  }
  float w2r[16];
#pragma unroll
  for (int jj = 0; jj < 16; jj++) w2r[jj] = mw2[lhi * 16 + jj];
  const float b2s = mb2[0];

  const int ntiles = NP / 64;  // 6250
  for (int tile = blockIdx.x; tile < ntiles; tile += gridDim.x) {
    const int pbase = tile * 64 + wid * 16;
#pragma unroll
    for (int rr = 0; rr < 4; rr++) {
      int r = rr * 4 + lhi;
      int p = pbase + r;
      int s = ei[p], d = ei[NEDGE + p];
      f16x8 hv = *(const f16x8*)(h + (size_t)s * HD + l15 * 8);
      f16x8 gv = *(const f16x8*)(h + (size_t)d * HD + l15 * 8);
      f16x8 pv = hv * gv;
      f16x8 qv = hv - gv;
      u16x8 qb = *(u16x8*)&qv;
#pragma unroll
      for (int u = 0; u < 8; u++) qb[u] &= 0x7FFF;
      qv = *(f16x8*)&qb;
      *(f16x8*)(&At[wid][r * 264 + l15 * 8]) = pv;
      *(f16x8*)(&At[wid][r * 264 + 128 + l15 * 8]) = qv;
    }
    if (lane < 16) {
      int p = pbase + lane;
      int s = ei[p], d = ei[NEDGE + p];
      float a = logdeg[s], b = logdeg[d];
      sfeat[wid][0][lane] = a + b;
      sfeat[wid][1][lane] = fabsf(a - b);
      en_pair[p] = rsq[s] * rsq[d];
    }
    __syncthreads();
    f32x4 acc[4] = {{0.f, 0.f, 0.f, 0.f}, {0.f, 0.f, 0.f, 0.f},
                    {0.f, 0.f, 0.f, 0.f}, {0.f, 0.f, 0.f, 0.f}};
#pragma unroll
    for (int ks = 0; ks < 8; ks++) {
      f16x8 af = *(const f16x8*)(&At[wid][l15 * 264 + ks * 32 + lhi * 8]);
#pragma unroll
      for (int t = 0; t < 4; t++)
        acc[t] = __builtin_amdgcn_mfma_f32_16x16x32_f16(af, bfr[ks][t], acc[t], 0, 0, 0);
    }
#pragma unroll
    for (int t = 0; t < 4; t++) {
#pragma unroll
      for (int i = 0; i < 4; i++) {
        int r = lhi * 4 + i;
        float v = acc[t][i] + sfeat[wid][0][r] * w256v[t] + sfeat[wid][1][r] * w257v[t] + b1v[t];
        hidl[wid][r * 64 + l15 + 16 * t] = fmaxf(v, 0.f);
      }
    }
    __syncthreads();
    {
      float sacc = 0.f;
#pragma unroll
      for (int jj = 0; jj < 16; jj++) sacc += hidl[wid][l15 * 64 + lhi * 16 + jj] * w2r[jj];
      sacc += __shfl_xor(sacc, 16);
      sacc += __shfl_xor(sacc, 32);
      if (lane < 16) {
        float wr = sacc + b2s;
        w_pair[pbase + lane] = 0.8f / (1.f + __expf(-wr));
      }
    }
    __syncthreads();
  }
}

// ---------------- m0 = exp(log_phi[src]) (edge-major) ----------------
__global__ __launch_bounds__(256) void k_m0(const int* __restrict__ ei,
    const float* __restrict__ logphi, float* __restrict__ m) {
  int e = blockIdx.x * 256 + threadIdx.x;
  if (e >= NEDGE) return;
  int s = ei[e];
  float2* mp = (float2*)(m + (size_t)e * 10);
  const float2* lp = (const float2*)(logphi + (size_t)s * 10);
#pragma unroll
  for (int i = 0; i < 5; i++) {
    float2 v = lp[i];
    float2 o;
    o.x = __expf(v.x);
    o.y = __expf(v.y);
    mp[i] = o;
  }
}

// ---------------- BP message: f, L (no atomics) ----------------
__global__ __launch_bounds__(256) void k_bp_f(const float* __restrict__ m,
    const float* __restrict__ wp, const float* __restrict__ enp,
    const float* __restrict__ Rbuf, float* __restrict__ L) {
  __shared__ float Rs[100];
  if (threadIdx.x < 100) Rs[threadIdx.x] = Rbuf[threadIdx.x];
  __syncthreads();
  int e = blockIdx.x * 256 + threadIdx.x;
  if (e >= NEDGE) return;
  int p = (e < NP) ? e : e - NP;
  float w = wp[p], en = enp[p];
  float mr[10];
  {
    const float2* mp = (const float2*)(m + (size_t)e * 10);
#pragma unroll
    for (int i = 0; i < 5; i++) { float2 v = mp[i]; mr[2 * i] = v.x; mr[2 * i + 1] = v.y; }
  }
  float f[10] = {0, 0, 0, 0, 0, 0, 0, 0, 0, 0};
  // R symmetric: compute 55 exps instead of 100
#pragma unroll
  for (int c = 0; c < NC; c++) {
    float Ecc = __expf(w * Rs[c * NC + c]);
    f[c] += mr[c] * Ecc;
#pragma unroll
    for (int d = c + 1; d < NC; d++) {
      float Ecd = __expf(w * Rs[c * NC + d]);
      f[d] += mr[c] * Ecd;
      f[c] += mr[d] * Ecd;
    }
  }
  float2* Lp = (float2*)(L + (size_t)e * 10);
#pragma unroll
  for (int i = 0; i < 5; i++) {
    float2 o;
    o.x = __logf(fmaxf(f[2 * i], 1e-12f)) * en;
    o.y = __logf(fmaxf(f[2 * i + 1], 1e-12f)) * en;
    Lp[i] = o;
  }
}

// ---------------- gather segment-reduce: sum_in[n][c] = sum L[incoming][c] ----------------
__global__ __launch_bounds__(256) void k_gather(const float* __restrict__ L,
    const int* __restrict__ csr, const int* __restrict__ off, float* __restrict__ sumin) {
  int wave = (blockIdx.x * 256 + threadIdx.x) >> 6;
  int lane = threadIdx.x & 63;
  int nl = lane / 10;   // 0..5 (6 nodes per wave), lanes 60..63 idle
  int c = lane % 10;
  int n = wave * 6 + nl;
  if (nl >= 6 || n >= NN) return;
  int o0 = off[n], o1 = off[n + 1];
  float acc = 0.f;
  for (int k = o0; k < o1; k++) {
    int e = csr[k];
    acc += L[(size_t)e * 10 + c];
  }
  sumin[(size_t)n * 10 + c] = acc;
}

// ---------------- BP update: m mix + renorm ----------------
__global__ __launch_bounds__(256) void k_bp_upd(float* __restrict__ m,
    const float* __restrict__ L, const float* __restrict__ sumin,
    const float* __restrict__ logphi, const int* __restrict__ ei,
    const float* __restrict__ Rbuf) {
  int e = blockIdx.x * 256 + threadIdx.x;
  if (e >= NEDGE) return;
  int s = ei[e];
  int re = (e < NP) ? e + NP : e - NP;  // rev[e] by construction
  float alpha = Rbuf[100];
  float t[NC];
  float mx = -1e30f;
  {
    const float2* Lr = (const float2*)(L + (size_t)re * 10);
    const float2* si = (const float2*)(sumin + (size_t)s * 10);
    const float2* lp = (const float2*)(logphi + (size_t)s * 10);
#pragma unroll
    for (int i = 0; i < 5; i++) {
      float2 lv = Lr[i], sv = si[i], pv = lp[i];
      float v0 = pv.x + alpha * (sv.x - lv.x);
      float v1 = pv.y + alpha * (sv.y - lv.y);
      t[2 * i] = v0;
      t[2 * i + 1] = v1;
      mx = fmaxf(mx, fmaxf(v0, v1));
    }
  }
  float ssum = 0.f;
#pragma unroll
  for (int c = 0; c < NC; c++) { float ev = __expf(t[c] - mx); t[c] = ev; ssum += ev; }
  float inv = 1.f / ssum;
  float nsum = 0.f;
  float2* mp = (float2*)(m + (size_t)e * 10);
  float mr[10];
  {
#pragma unroll
    for (int i = 0; i < 5; i++) { float2 v = mp[i]; mr[2 * i] = v.x; mr[2 * i + 1] = v.y; }
  }
#pragma unroll
  for (int c = 0; c < NC; c++) {
    float mm = 0.8f * mr[c] + 0.2f * (t[c] * inv);
    mm = fmaxf(mm, 1e-12f);
    t[c] = mm;
    nsum += mm;
  }
  float inv2 = 1.f / nsum;
#pragma unroll
  for (int i = 0; i < 5; i++) {
    float2 o;
    o.x = t[2 * i] * inv2;
    o.y = t[2 * i + 1] * inv2;
    mp[i] = o;
  }
}

// ---------------- final beliefs ----------------
__global__ __launch_bounds__(256) void k_beliefs(const float* __restrict__ logphi,
    const float* __restrict__ sum_in, const float* __restrict__ Rbuf, float* __restrict__ out) {
  int n = blockIdx.x * 256 + threadIdx.x;
  if (n >= NN) return;
  float alpha = Rbuf[100];
  float t[NC];
  float mx = -1e30f;
#pragma unroll
  for (int c = 0; c < NC; c++) {
    float v = logphi[n * NC + c] + alpha * sum_in[n * NC + c];
    t[c] = v;
    mx = fmaxf(mx, v);
  }
  float ssum = 0.f;
#pragma unroll
  for (int c = 0; c < NC; c++) { float ev = __expf(t[c] - mx); t[c] = ev; ssum += ev; }
  float inv = 1.f / ssum;
#pragma unroll
  for (int c = 0; c < NC; c++) out[(size_t)n * NC + c] = t[c] * inv;
}

extern "C" void kernel_launch(void* const* d_in, const int* in_sizes, int n_in,
                              void* d_out, int out_size, void* d_ws, size_t ws_size,
                              hipStream_t stream) {
  const float* x    = (const float*)d_in[0];
  const int*   ei   = (const int*)d_in[1];
  const float* ew1  = (const float*)d_in[3];
  const float* eb1  = (const float*)d_in[4];
  const float* ew2  = (const float*)d_in[5];
  const float* eb2  = (const float*)d_in[6];
  const float* mw1  = (const float*)d_in[7];
  const float* mb1  = (const float*)d_in[8];
  const float* mw2  = (const float*)d_in[9];
  const float* mb2  = (const float*)d_in[10];
  const float* Rraw = (const float*)d_in[11];
  const float* rsl  = (const float*)d_in[12];
  const float* ml   = (const float*)d_in[13];
  float* out = (float*)d_out;

  char* ws = (char*)d_ws;
  float* Rbuf   = (float*)(ws + OFF_R);
  f16*   h      = (f16*)(ws + OFF_H);
  int*   offs   = (int*)(ws + OFF_OFFS);
  int*   cursor = (int*)(ws + OFF_CUR);
  int*   csr    = (int*)(ws + OFF_CSR);
  float* logphi = (float*)(ws + OFF_LOGPHI);
  float* deg    = (float*)(ws + OFF_DEG);
  float* logdeg = (float*)(ws + OFF_LOGDEG);
  float* rsq    = (float*)(ws + OFF_RSQ);
  float* wpair  = (float*)(ws + OFF_WPAIR);
  float* enp    = (float*)(ws + OFF_EN);
  float* m      = (float*)(ws + OFF_M);
  float* L      = (float*)(ws + OFF_L);
  float* sumin  = (float*)(ws + OFF_SUMIN);
  f16*   w1t    = (f16*)(ws + OFF_W1T);

  k_setup<<<1, 256, 0, stream>>>(Rraw, rsl, ml, mw1, Rbuf, w1t);
  hipMemsetAsync(deg, 0, NN * sizeof(float), stream);
  k_deg<<<NEDGE / 256, 256, 0, stream>>>(ei, deg);
  k_nodepost<<<(NN + 255) / 256, 256, 0, stream>>>(deg, logdeg, rsq);
  k_encoder<<<NN / 16, 256, 0, stream>>>(x, ew1, eb1, h);
  k_logits<<<NN / 16, 256, 0, stream>>>(h, ew2, eb2, logphi);
  k_edge_mlp<<<512, 256, 0, stream>>>(h, ei, logdeg, rsq, w1t, mw1, mb1, mw2, mb2, wpair, enp);
  // CSR build (h region is dead from here on)
  k_scan<<<1, 1024, 0, stream>>>(deg, offs, cursor);
  k_fill<<<NEDGE / 256, 256, 0, stream>>>(ei, cursor, csr);
  k_m0<<<NEDGE / 256, 256, 0, stream>>>(ei, logphi, m);

  const int gblocks = (NN + 23) / 24;  // 4 waves/block * 6 nodes/wave
  for (int it = 0; it < TBP; it++) {
    k_bp_f<<<NEDGE / 256, 256, 0, stream>>>(m, wpair, enp, Rbuf, L);
    k_gather<<<gblocks, 256, 0, stream>>>(L, csr, offs, sumin);
    k_bp_upd<<<NEDGE / 256, 256, 0, stream>>>(m, L, sumin, logphi, ei, Rbuf);
  }
  k_bp_f<<<NEDGE / 256, 256, 0, stream>>>(m, wpair, enp, Rbuf, L);
  k_gather<<<gblocks, 256, 0, stream>>>(L, csr, offs, sumin);
  k_beliefs<<<(NN + 255) / 256, 256, 0, stream>>>(logphi, sumin, Rbuf, out);
}

// Round 5
// 1242.942 us; speedup vs baseline: 4.1598x; 1.0916x over previous
//
#include <hip/hip_runtime.h>
#include <hip/hip_fp16.h>

#define NN 50000
#define NP 400000
#define NEDGE 800000
#define IND 256
#define HD 128
#define NC 10
#define TBP 10
#define SCAN_NB 196  // ceil(NN/256)

typedef _Float16 f16;
typedef _Float16 f16x8 __attribute__((ext_vector_type(8)));
typedef unsigned short u16x8 __attribute__((ext_vector_type(8)));
typedef float f32x4 __attribute__((ext_vector_type(4)));

// ---- workspace offsets (bytes) ----
static constexpr size_t OFF_R      = 0;          // 128 f32: R[100], [100]=alpha
static constexpr size_t OFF_H      = 512;        // h fp16 [NN][128] (dead after edge_mlp)
static constexpr size_t OFF_OFFS   = 512;            // CSR off int[NN+1]   (aliases h)
static constexpr size_t OFF_CUR    = 512 + 200016;   // CSR cursor int[NN]  (aliases h)
static constexpr size_t OFF_CSR    = 512 + 400032;   // CSR edge ids int[NEDGE] (aliases h)
static constexpr size_t OFF_BSUM   = 512 + 3600032;  // int[256] block sums (aliases h)
static constexpr size_t OFF_BBASE  = 512 + 3601056;  // int[256] block bases (aliases h)
static constexpr size_t OFF_LOGPHI = 12800512;   // [NN][10] f32
static constexpr size_t OFF_DEG    = 14800512;   // [NN] f32
static constexpr size_t OFF_LOGDEG = 15000512;   // [NN] f32
static constexpr size_t OFF_RSQ    = 15200512;   // [NN] f32
static constexpr size_t OFF_WPAIR  = 15400512;   // [NP] f32
static constexpr size_t OFF_EN     = 17000512;   // [NP] f32
static constexpr size_t OFF_M      = 18600512;   // m edge-major [NEDGE][10] f32 (32MB)
static constexpr size_t OFF_L      = 50600512;   // log_f edge-major [NEDGE][10] f32 (32MB)
static constexpr size_t OFF_SUMIN  = 82600512;   // [NN][10] f32
static constexpr size_t OFF_W1T    = 84600512;   // W1 transposed fp16 [64][256]

// ---------------- setup: R matrix, alpha, W1 transpose ----------------
__global__ __launch_bounds__(256) void k_setup(const float* __restrict__ Rraw,
    const float* __restrict__ rsl, const float* __restrict__ ml,
    const float* __restrict__ mw1, float* __restrict__ Rbuf, f16* __restrict__ w1t) {
  int tid = threadIdx.x;
  if (tid < 100) {
    int c = tid / 10, d = tid % 10;
    float scale = log1pf(expf(rsl[0])) + 1e-6f;
    Rbuf[tid] = scale * tanhf(0.5f * (Rraw[c * 10 + d] + Rraw[d * 10 + c]));
  } else if (tid == 100) {
    Rbuf[100] = 1.5f * (1.f / (1.f + expf(-ml[0])));  // ALPHA_MAX*sigmoid*ALPHA_SCALE
  }
  for (int idx = tid; idx < 64 * 256; idx += 256) {
    int j = idx >> 8, k = idx & 255;
    w1t[idx] = (f16)mw1[k * 64 + j];
  }
}

// ---------------- degree / node post ----------------
__global__ __launch_bounds__(256) void k_deg(const int* __restrict__ ei, float* __restrict__ deg) {
  int e = blockIdx.x * 256 + threadIdx.x;
  if (e < NEDGE) atomicAdd(&deg[ei[e]], 1.f);
}

__global__ __launch_bounds__(256) void k_nodepost(const float* __restrict__ deg,
    float* __restrict__ logdeg, float* __restrict__ rsq) {
  int i = blockIdx.x * 256 + threadIdx.x;
  if (i >= NN) return;
  float d = deg[i];
  logdeg[i] = __logf(d + 1.f);
  rsq[i] = rsqrtf(fmaxf(d, 1.f));
}

// ---------------- CSR build: 3-phase hierarchical scan ----------------
__global__ __launch_bounds__(256) void k_scan1(const float* __restrict__ deg,
    int* __restrict__ bsum) {
  int idx = blockIdx.x * 256 + threadIdx.x;
  int v = (idx < NN) ? (int)deg[idx] : 0;
#pragma unroll
  for (int o = 32; o; o >>= 1) v += __shfl_down(v, o);
  __shared__ int wsum[4];
  if ((threadIdx.x & 63) == 0) wsum[threadIdx.x >> 6] = v;
  __syncthreads();
  if (threadIdx.x == 0) bsum[blockIdx.x] = wsum[0] + wsum[1] + wsum[2] + wsum[3];
}

__global__ __launch_bounds__(256) void k_scan2(const int* __restrict__ bsum,
    int* __restrict__ bbase) {
  __shared__ int s[256];
  int t = threadIdx.x;
  int orig = (t < SCAN_NB) ? bsum[t] : 0;
  s[t] = orig;
  __syncthreads();
  for (int d = 1; d < 256; d <<= 1) {
    int v = (t >= d) ? s[t - d] : 0;
    __syncthreads();
    s[t] += v;
    __syncthreads();
  }
  bbase[t] = s[t] - orig;  // exclusive
}

__global__ __launch_bounds__(256) void k_scan3(const float* __restrict__ deg,
    const int* __restrict__ bbase, int* __restrict__ off, int* __restrict__ cursor) {
  __shared__ int s[256];
  int t = threadIdx.x;
  int idx = blockIdx.x * 256 + t;
  int d = (idx < NN) ? (int)deg[idx] : 0;
  s[t] = d;
  __syncthreads();
  for (int k = 1; k < 256; k <<= 1) {
    int v = (t >= k) ? s[t - k] : 0;
    __syncthreads();
    s[t] += v;
    __syncthreads();
  }
  int base = bbase[blockIdx.x];
  int excl = base + s[t] - d;
  if (idx < NN) {
    off[idx] = excl;
    cursor[idx] = excl;
  }
  if (idx == NN - 1) off[NN] = excl + d;
}

__global__ __launch_bounds__(256) void k_fill(const int* __restrict__ ei,
    int* __restrict__ cursor, int* __restrict__ csr) {
  int e = blockIdx.x * 256 + threadIdx.x;
  if (e >= NEDGE) return;
  int d = ei[NEDGE + e];
  int pos = atomicAdd(&cursor[d], 1);
  csr[pos] = e;
}

// ---------------- encoder: h = relu(x @ W1 + b1), store fp16 ----------------
__global__ __launch_bounds__(256) void k_encoder(const float* __restrict__ x,
    const float* __restrict__ w1, const float* __restrict__ b1, f16* __restrict__ h) {
  __shared__ float xs[16 * IND];
  const int tid = threadIdx.x;
  const int nb = blockIdx.x * 16;
  {
    const float4* src = (const float4*)(x + (size_t)nb * IND);
    float4* dst4 = (float4*)xs;
#pragma unroll
    for (int i = 0; i < 4; i++) dst4[tid + 256 * i] = src[tid + 256 * i];
  }
  __syncthreads();
  const int j = tid & (HD - 1);
  const int g = tid >> 7;
  float acc[8] = {0, 0, 0, 0, 0, 0, 0, 0};
  const float4* xs4 = (const float4*)xs;
  for (int k0 = 0; k0 < IND; k0 += 4) {
    float wa = w1[(k0 + 0) * HD + j];
    float wb = w1[(k0 + 1) * HD + j];
    float wc = w1[(k0 + 2) * HD + j];
    float wd = w1[(k0 + 3) * HD + j];
#pragma unroll
    for (int n = 0; n < 8; n++) {
      float4 xv = xs4[(g * 8 + n) * (IND / 4) + (k0 >> 2)];
      acc[n] += xv.x * wa + xv.y * wb + xv.z * wc + xv.w * wd;
    }
  }
  float bj = b1[j];
#pragma unroll
  for (int n = 0; n < 8; n++) {
    float v = fmaxf(acc[n] + bj, 0.f);
    h[(size_t)(nb + g * 8 + n) * HD + j] = (f16)v;
  }
}

// ---------------- logits + log_softmax(logits/1.5) ----------------
__global__ __launch_bounds__(256) void k_logits(const f16* __restrict__ h,
    const float* __restrict__ w2, const float* __restrict__ b2, float* __restrict__ logphi) {
  __shared__ float hs[16 * HD];
  __shared__ float lg[16 * NC];
  const int tid = threadIdx.x;
  const int nb = blockIdx.x * 16;
  for (int i = tid; i < 16 * HD / 8; i += 256) {
    f16x8 v = *(const f16x8*)(h + (size_t)nb * HD + i * 8);
#pragma unroll
    for (int u = 0; u < 8; u++) hs[i * 8 + u] = (float)v[u];
  }
  __syncthreads();
  if (tid < 160) {
    int n = tid / 10, c = tid % 10;
    float a = b2[c];
    for (int k = 0; k < HD; k++) a += hs[n * HD + k] * w2[k * NC + c];
    lg[n * NC + c] = a * (1.f / 1.5f);
  }
  __syncthreads();
  if (tid < 16) {
    float mx = -1e30f;
#pragma unroll
    for (int c = 0; c < NC; c++) mx = fmaxf(mx, lg[tid * NC + c]);
    float s = 0.f;
#pragma unroll
    for (int c = 0; c < NC; c++) s += __expf(lg[tid * NC + c] - mx);
    float lse = __logf(s) + mx;
#pragma unroll
    for (int c = 0; c < NC; c++)
      logphi[(size_t)(nb + tid) * NC + c] = lg[tid * NC + c] - lse;
  }
}

// ---------------- edge MLP (per undirected pair), MFMA f16 ----------------
__global__ __launch_bounds__(256) void k_edge_mlp(const f16* __restrict__ h,
    const int* __restrict__ ei, const float* __restrict__ logdeg, const float* __restrict__ rsq,
    const f16* __restrict__ w1t, const float* __restrict__ mw1, const float* __restrict__ mb1,
    const float* __restrict__ mw2, const float* __restrict__ mb2,
    float* __restrict__ w_pair, float* __restrict__ en_pair) {
  __shared__ f16 At[4][16 * 264];
  __shared__ float hidl[4][16 * 64];
  __shared__ float sfeat[4][2][16];
  const int tid = threadIdx.x;
  const int wid = tid >> 6;
  const int lane = tid & 63;
  const int l15 = lane & 15;
  const int lhi = lane >> 4;

  f16x8 bfr[8][4];
#pragma unroll
  for (int ks = 0; ks < 8; ks++)
#pragma unroll
    for (int t = 0; t < 4; t++)
      bfr[ks][t] = *(const f16x8*)(w1t + (size_t)(l15 + 16 * t) * 256 + ks * 32 + lhi * 8);

  float b1v[4], w256v[4], w257v[4];
#pragma unroll
  for (int t = 0; t < 4; t++) {
    b1v[t] = mb1[l15 + 16 * t];
    w256v[t] = mw1[256 * 64 + l15 + 16 * t];
    w257v[t] = mw1[257 * 64 + l15 + 16 * t];
  }
  float w2r[16];
#pragma unroll
  for (int jj = 0; jj < 16; jj++) w2r[jj] = mw2[lhi * 16 + jj];
  const float b2s = mb2[0];

  const int ntiles = NP / 64;  // 6250
  for (int tile = blockIdx.x; tile < ntiles; tile += gridDim.x) {
    const int pbase = tile * 64 + wid * 16;
#pragma unroll
    for (int rr = 0; rr < 4; rr++) {
      int r = rr * 4 + lhi;
      int p = pbase + r;
      int s = ei[p], d = ei[NEDGE + p];
      f16x8 hv = *(const f16x8*)(h + (size_t)s * HD + l15 * 8);
      f16x8 gv = *(const f16x8*)(h + (size_t)d * HD + l15 * 8);
      f16x8 pv = hv * gv;
      f16x8 qv = hv - gv;
      u16x8 qb = *(u16x8*)&qv;
#pragma unroll
      for (int u = 0; u < 8; u++) qb[u] &= 0x7FFF;
      qv = *(f16x8*)&qb;
      *(f16x8*)(&At[wid][r * 264 + l15 * 8]) = pv;
      *(f16x8*)(&At[wid][r * 264 + 128 + l15 * 8]) = qv;
    }
    if (lane < 16) {
      int p = pbase + lane;
      int s = ei[p], d = ei[NEDGE + p];
      float a = logdeg[s], b = logdeg[d];
      sfeat[wid][0][lane] = a + b;
      sfeat[wid][1][lane] = fabsf(a - b);
      en_pair[p] = rsq[s] * rsq[d];
    }
    __syncthreads();
    f32x4 acc[4] = {{0.f, 0.f, 0.f, 0.f}, {0.f, 0.f, 0.f, 0.f},
                    {0.f, 0.f, 0.f, 0.f}, {0.f, 0.f, 0.f, 0.f}};
#pragma unroll
    for (int ks = 0; ks < 8; ks++) {
      f16x8 af = *(const f16x8*)(&At[wid][l15 * 264 + ks * 32 + lhi * 8]);
#pragma unroll
      for (int t = 0; t < 4; t++)
        acc[t] = __builtin_amdgcn_mfma_f32_16x16x32_f16(af, bfr[ks][t], acc[t], 0, 0, 0);
    }
#pragma unroll
    for (int t = 0; t < 4; t++) {
#pragma unroll
      for (int i = 0; i < 4; i++) {
        int r = lhi * 4 + i;
        float v = acc[t][i] + sfeat[wid][0][r] * w256v[t] + sfeat[wid][1][r] * w257v[t] + b1v[t];
        hidl[wid][r * 64 + l15 + 16 * t] = fmaxf(v, 0.f);
      }
    }
    __syncthreads();
    {
      float sacc = 0.f;
#pragma unroll
      for (int jj = 0; jj < 16; jj++) sacc += hidl[wid][l15 * 64 + lhi * 16 + jj] * w2r[jj];
      sacc += __shfl_xor(sacc, 16);
      sacc += __shfl_xor(sacc, 32);
      if (lane < 16) {
        float wr = sacc + b2s;
        w_pair[pbase + lane] = 0.8f / (1.f + __expf(-wr));
      }
    }
    __syncthreads();
  }
}

// ---------------- m0 = exp(log_phi[src]) (edge-major) ----------------
__global__ __launch_bounds__(256) void k_m0(const int* __restrict__ ei,
    const float* __restrict__ logphi, float* __restrict__ m) {
  int e = blockIdx.x * 256 + threadIdx.x;
  if (e >= NEDGE) return;
  int s = ei[e];
  float2* mp = (float2*)(m + (size_t)e * 10);
  const float2* lp = (const float2*)(logphi + (size_t)s * 10);
#pragma unroll
  for (int i = 0; i < 5; i++) {
    float2 v = lp[i];
    float2 o;
    o.x = __expf(v.x);
    o.y = __expf(v.y);
    mp[i] = o;
  }
}

// ---------------- BP message: f, L (no atomics) ----------------
__global__ __launch_bounds__(256) void k_bp_f(const float* __restrict__ m,
    const float* __restrict__ wp, const float* __restrict__ enp,
    const float* __restrict__ Rbuf, float* __restrict__ L) {
  __shared__ float Rs[100];
  if (threadIdx.x < 100) Rs[threadIdx.x] = Rbuf[threadIdx.x];
  __syncthreads();
  int e = blockIdx.x * 256 + threadIdx.x;
  if (e >= NEDGE) return;
  int p = (e < NP) ? e : e - NP;
  float w = wp[p], en = enp[p];
  float mr[10];
  {
    const float2* mp = (const float2*)(m + (size_t)e * 10);
#pragma unroll
    for (int i = 0; i < 5; i++) { float2 v = mp[i]; mr[2 * i] = v.x; mr[2 * i + 1] = v.y; }
  }
  float f[10] = {0, 0, 0, 0, 0, 0, 0, 0, 0, 0};
  // R symmetric: compute 55 exps instead of 100
#pragma unroll
  for (int c = 0; c < NC; c++) {
    float Ecc = __expf(w * Rs[c * NC + c]);
    f[c] += mr[c] * Ecc;
#pragma unroll
    for (int d = c + 1; d < NC; d++) {
      float Ecd = __expf(w * Rs[c * NC + d]);
      f[d] += mr[c] * Ecd;
      f[c] += mr[d] * Ecd;
    }
  }
  float2* Lp = (float2*)(L + (size_t)e * 10);
#pragma unroll
  for (int i = 0; i < 5; i++) {
    float2 o;
    o.x = __logf(fmaxf(f[2 * i], 1e-12f)) * en;
    o.y = __logf(fmaxf(f[2 * i + 1], 1e-12f)) * en;
    Lp[i] = o;
  }
}

// ---------------- gather segment-reduce: sum_in[n][c] = sum L[incoming][c] ----------------
__global__ __launch_bounds__(256) void k_gather(const float* __restrict__ L,
    const int* __restrict__ csr, const int* __restrict__ off, float* __restrict__ sumin) {
  int wave = (blockIdx.x * 256 + threadIdx.x) >> 6;
  int lane = threadIdx.x & 63;
  int nl = lane / 10;   // 0..5 (6 nodes per wave), lanes 60..63 idle
  int c = lane % 10;
  int n = wave * 6 + nl;
  if (nl >= 6 || n >= NN) return;
  int o0 = off[n], o1 = off[n + 1];
  float acc = 0.f;
  for (int k = o0; k < o1; k++) {
    int e = csr[k];
    acc += L[(size_t)e * 10 + c];
  }
  sumin[(size_t)n * 10 + c] = acc;
}

// ---------------- BP update: m mix + renorm ----------------
__global__ __launch_bounds__(256) void k_bp_upd(float* __restrict__ m,
    const float* __restrict__ L, const float* __restrict__ sumin,
    const float* __restrict__ logphi, const int* __restrict__ ei,
    const float* __restrict__ Rbuf) {
  int e = blockIdx.x * 256 + threadIdx.x;
  if (e >= NEDGE) return;
  int s = ei[e];
  int re = (e < NP) ? e + NP : e - NP;  // rev[e] by construction
  float alpha = Rbuf[100];
  float t[NC];
  float mx = -1e30f;
  {
    const float2* Lr = (const float2*)(L + (size_t)re * 10);
    const float2* si = (const float2*)(sumin + (size_t)s * 10);
    const float2* lp = (const float2*)(logphi + (size_t)s * 10);
#pragma unroll
    for (int i = 0; i < 5; i++) {
      float2 lv = Lr[i], sv = si[i], pv = lp[i];
      float v0 = pv.x + alpha * (sv.x - lv.x);
      float v1 = pv.y + alpha * (sv.y - lv.y);
      t[2 * i] = v0;
      t[2 * i + 1] = v1;
      mx = fmaxf(mx, fmaxf(v0, v1));
    }
  }
  float ssum = 0.f;
#pragma unroll
  for (int c = 0; c < NC; c++) { float ev = __expf(t[c] - mx); t[c] = ev; ssum += ev; }
  float inv = 1.f / ssum;
  float nsum = 0.f;
  float2* mp = (float2*)(m + (size_t)e * 10);
  float mr[10];
  {
#pragma unroll
    for (int i = 0; i < 5; i++) { float2 v = mp[i]; mr[2 * i] = v.x; mr[2 * i + 1] = v.y; }
  }
#pragma unroll
  for (int c = 0; c < NC; c++) {
    float mm = 0.8f * mr[c] + 0.2f * (t[c] * inv);
    mm = fmaxf(mm, 1e-12f);
    t[c] = mm;
    nsum += mm;
  }
  float inv2 = 1.f / nsum;
#pragma unroll
  for (int i = 0; i < 5; i++) {
    float2 o;
    o.x = t[2 * i] * inv2;
    o.y = t[2 * i + 1] * inv2;
    mp[i] = o;
  }
}

// ---------------- final beliefs ----------------
__global__ __launch_bounds__(256) void k_beliefs(const float* __restrict__ logphi,
    const float* __restrict__ sum_in, const float* __restrict__ Rbuf, float* __restrict__ out) {
  int n = blockIdx.x * 256 + threadIdx.x;
  if (n >= NN) return;
  float alpha = Rbuf[100];
  float t[NC];
  float mx = -1e30f;
#pragma unroll
  for (int c = 0; c < NC; c++) {
    float v = logphi[n * NC + c] + alpha * sum_in[n * NC + c];
    t[c] = v;
    mx = fmaxf(mx, v);
  }
  float ssum = 0.f;
#pragma unroll
  for (int c = 0; c < NC; c++) { float ev = __expf(t[c] - mx); t[c] = ev; ssum += ev; }
  float inv = 1.f / ssum;
#pragma unroll
  for (int c = 0; c < NC; c++) out[(size_t)n * NC + c] = t[c] * inv;
}

extern "C" void kernel_launch(void* const* d_in, const int* in_sizes, int n_in,
                              void* d_out, int out_size, void* d_ws, size_t ws_size,
                              hipStream_t stream) {
  const float* x    = (const float*)d_in[0];
  const int*   ei   = (const int*)d_in[1];
  const float* ew1  = (const float*)d_in[3];
  const float* eb1  = (const float*)d_in[4];
  const float* ew2  = (const float*)d_in[5];
  const float* eb2  = (const float*)d_in[6];
  const float* mw1  = (const float*)d_in[7];
  const float* mb1  = (const float*)d_in[8];
  const float* mw2  = (const float*)d_in[9];
  const float* mb2  = (const float*)d_in[10];
  const float* Rraw = (const float*)d_in[11];
  const float* rsl  = (const float*)d_in[12];
  const float* ml   = (const float*)d_in[13];
  float* out = (float*)d_out;

  char* ws = (char*)d_ws;
  float* Rbuf   = (float*)(ws + OFF_R);
  f16*   h      = (f16*)(ws + OFF_H);
  int*   offs   = (int*)(ws + OFF_OFFS);
  int*   cursor = (int*)(ws + OFF_CUR);
  int*   csr    = (int*)(ws + OFF_CSR);
  int*   bsum   = (int*)(ws + OFF_BSUM);
  int*   bbase  = (int*)(ws + OFF_BBASE);
  float* logphi = (float*)(ws + OFF_LOGPHI);
  float* deg    = (float*)(ws + OFF_DEG);
  float* logdeg = (float*)(ws + OFF_LOGDEG);
  float* rsq    = (float*)(ws + OFF_RSQ);
  float* wpair  = (float*)(ws + OFF_WPAIR);
  float* enp    = (float*)(ws + OFF_EN);
  float* m      = (float*)(ws + OFF_M);
  float* L      = (float*)(ws + OFF_L);
  float* sumin  = (float*)(ws + OFF_SUMIN);
  f16*   w1t    = (f16*)(ws + OFF_W1T);

  k_setup<<<1, 256, 0, stream>>>(Rraw, rsl, ml, mw1, Rbuf, w1t);
  hipMemsetAsync(deg, 0, NN * sizeof(float), stream);
  k_deg<<<NEDGE / 256, 256, 0, stream>>>(ei, deg);
  k_nodepost<<<(NN + 255) / 256, 256, 0, stream>>>(deg, logdeg, rsq);
  k_encoder<<<NN / 16, 256, 0, stream>>>(x, ew1, eb1, h);
  k_logits<<<NN / 16, 256, 0, stream>>>(h, ew2, eb2, logphi);
  k_edge_mlp<<<512, 256, 0, stream>>>(h, ei, logdeg, rsq, w1t, mw1, mb1, mw2, mb2, wpair, enp);
  // CSR build (h region is dead from here on)
  k_scan1<<<SCAN_NB, 256, 0, stream>>>(deg, bsum);
  k_scan2<<<1, 256, 0, stream>>>(bsum, bbase);
  k_scan3<<<SCAN_NB, 256, 0, stream>>>(deg, bbase, offs, cursor);
  k_fill<<<NEDGE / 256, 256, 0, stream>>>(ei, cursor, csr);
  k_m0<<<NEDGE / 256, 256, 0, stream>>>(ei, logphi, m);

  const int gblocks = (NN + 23) / 24;  // 4 waves/block * 6 nodes/wave
  for (int it = 0; it < TBP; it++) {
    k_bp_f<<<NEDGE / 256, 256, 0, stream>>>(m, wpair, enp, Rbuf, L);
    k_gather<<<gblocks, 256, 0, stream>>>(L, csr, offs, sumin);
    k_bp_upd<<<NEDGE / 256, 256, 0, stream>>>(m, L, sumin, logphi, ei, Rbuf);
  }
  k_bp_f<<<NEDGE / 256, 256, 0, stream>>>(m, wpair, enp, Rbuf, L);
  k_gather<<<gblocks, 256, 0, stream>>>(L, csr, offs, sumin);
  k_beliefs<<<(NN + 255) / 256, 256, 0, stream>>>(logphi, sumin, Rbuf, out);
}